// Round 1
// baseline (1133.013 us; speedup 1.0000x reference)
//
#include <hip/hip_runtime.h>

typedef __attribute__((ext_vector_type(4))) float f32x4;
typedef __attribute__((ext_vector_type(8))) short s16x8;
typedef __attribute__((ext_vector_type(4))) short s16x4;
typedef unsigned short u16;

// ---------- helpers ----------
__device__ __forceinline__ u16 f2bf(float f) {
  union { float f; unsigned int u; } v; v.f = f;
  unsigned int r = v.u + 0x7fffu + ((v.u >> 16) & 1u);  // RNE
  return (u16)(r >> 16);
}

__device__ __forceinline__ void gload_lds16(const void* g, void* l) {
  __builtin_amdgcn_global_load_lds(
      (const __attribute__((address_space(1))) void*)g,
      (__attribute__((address_space(3))) void*)l, 16, 0, 0);
}

// ---------- elementwise f32 -> bf16 (vectorized) ----------
__global__ __launch_bounds__(256) void cvt_bf16(const float* __restrict__ in,
                                                u16* __restrict__ outp, int nquad) {
  int i = blockIdx.x * 256 + threadIdx.x;
  if (i >= nquad) return;
  f32x4 v = *(const f32x4*)(in + (size_t)i * 4);
  s16x4 o;
  o.x = (short)f2bf(v.x); o.y = (short)f2bf(v.y);
  o.z = (short)f2bf(v.z); o.w = (short)f2bf(v.w);
  *(s16x4*)(outp + (size_t)i * 4) = o;
}

// ---------- transpose + convert: in (R x C) f32 row-major -> out (C x R) bf16 ----------
__global__ __launch_bounds__(256) void transpose_cvt(const float* __restrict__ in,
                                                     u16* __restrict__ outp, int R, int C) {
  __shared__ float t[32][33];
  int c0 = blockIdx.x * 32, r0 = blockIdx.y * 32;
  int tx = threadIdx.x & 31, ty = threadIdx.x >> 5;  // 32 x 8
#pragma unroll
  for (int i = 0; i < 32; i += 8) t[ty + i][tx] = in[(size_t)(r0 + ty + i) * C + c0 + tx];
  __syncthreads();
#pragma unroll
  for (int i = 0; i < 32; i += 8)
    outp[(size_t)(c0 + ty + i) * R + r0 + tx] = f2bf(t[tx][ty + i]);
}

// ---------- RoPE table (matches the reference's interleaved-then-split layout) ----------
// tab[p*64+e] = (S_e, C_e):
//   S_e = e even ? sin(p*f_{e/2})    : cos(p*f_{e/2})
//   C_e = e even ? sin(p*f_{e/2+32}) : cos(p*f_{e/2+32}),  f_j = 1e6^{-j/64}
__global__ void rope_table(float2* __restrict__ tab) {
  int p = blockIdx.x, e = threadIdx.x;
  int j = e >> 1;
  float f1 = powf(1.0e6f, -(float)j / 64.0f);
  float f2 = powf(1.0e6f, -(float)(j + 32) / 64.0f);
  float a1 = (float)p * f1, a2 = (float)p * f2;
  float S = (e & 1) ? cosf(a1) : sinf(a1);
  float C = (e & 1) ? cosf(a2) : sinf(a2);
  tab[p * 64 + e] = make_float2(S, C);
}

// ---------- RoPE + head-pack: P (B*S x nh*128) f32 -> out [b][h][s][128] bf16 ----------
__global__ __launch_bounds__(256) void rope_pack(const float* __restrict__ P,
                                                 const float2* __restrict__ tab,
                                                 u16* __restrict__ outp, int nh) {
  int idx = blockIdx.x * 4 + (threadIdx.x >> 6);  // over (b*nh+h)*2048+s
  int e = threadIdx.x & 63;
  int s = idx & 2047;
  int bh = idx >> 11;
  int b = bh / nh, h = bh - b * nh;
  size_t prow = ((size_t)(b * 2048 + s)) * (size_t)(nh * 128) + (size_t)h * 128;
  float x1 = P[prow + e], x2 = P[prow + e + 64];
  float2 t = tab[s * 64 + e];
  float o1 = x1 * t.y - x2 * t.x;   // q*cos + rotate_half(q)*sin, d<64
  float o2 = x2 * t.y + x1 * t.x;   // d>=64
  size_t orow = (size_t)idx * 128;
  outp[orow + e] = f2bf(o1);
  outp[orow + e + 64] = f2bf(o2);
}

// ---------- V pack+transpose: Vp (B*S x 512) f32 -> Vt [b][kh][128][S] bf16 ----------
__global__ __launch_bounds__(256) void pack_vt(const float* __restrict__ Vp,
                                               u16* __restrict__ Vt) {
  __shared__ float t[32][33];
  int bk = blockIdx.z;               // b*4+kh
  int b = bk >> 2, kh = bk & 3;
  int s0 = blockIdx.x * 32, d0 = blockIdx.y * 32;
  int tx = threadIdx.x & 31, ty = threadIdx.x >> 5;
  const float* in = Vp + (size_t)(b * 2048) * 512 + kh * 128;
#pragma unroll
  for (int i = 0; i < 32; i += 8) t[ty + i][tx] = in[(size_t)(s0 + ty + i) * 512 + d0 + tx];
  __syncthreads();
  u16* outp = Vt + (size_t)bk * 128 * 2048;
#pragma unroll
  for (int i = 0; i < 32; i += 8)
    outp[(size_t)(d0 + ty + i) * 2048 + s0 + tx] = f2bf(t[tx][ty + i]);
}

// ---------- GEMM: C (MxN f32) = A (MxK bf16) * BT (NxK bf16)^T ; 128x128 tile, m97 structure ----------
__global__ __launch_bounds__(256) void gemm_bt(const u16* __restrict__ A,
                                               const u16* __restrict__ BT,
                                               float* __restrict__ C, int M, int N, int K) {
  __shared__ u16 lA[128 * 32];
  __shared__ u16 lB[128 * 32];
  const int tid = threadIdx.x;
  const int lane = tid & 63, wave = tid >> 6;
  const int bm = blockIdx.y * 128, bn = blockIdx.x * 128;
  const int wr = (wave >> 1) * 64, wc = (wave & 1) * 64;
  const int r = lane & 15, g = lane >> 4;

  f32x4 acc[4][4];
#pragma unroll
  for (int i = 0; i < 4; i++)
#pragma unroll
    for (int j = 0; j < 4; j++) acc[i][j] = (f32x4){0.f, 0.f, 0.f, 0.f};

  // staging: byte o = (wave*2+c)*1024 + lane*16 over the 8 KiB tile; row = o/64
  const int o0 = wave * 2048 + lane * 16;
  const int row0 = o0 >> 6, cb0 = (o0 & 63) >> 1;
  const int o1 = o0 + 1024;
  const int row1 = o1 >> 6, cb1 = (o1 & 63) >> 1;
  const u16* a0 = A + (size_t)(bm + row0) * K + cb0;
  const u16* a1 = A + (size_t)(bm + row1) * K + cb1;
  const u16* b0 = BT + (size_t)(bn + row0) * K + cb0;
  const u16* b1 = BT + (size_t)(bn + row1) * K + cb1;
  u16* lA0 = lA + wave * 2 * 512; u16* lA1 = lA + (wave * 2 + 1) * 512;
  u16* lB0 = lB + wave * 2 * 512; u16* lB1 = lB + (wave * 2 + 1) * 512;

  for (int kt = 0; kt < K; kt += 32) {
    __syncthreads();
    gload_lds16(a0 + kt, lA0);
    gload_lds16(a1 + kt, lA1);
    gload_lds16(b0 + kt, lB0);
    gload_lds16(b1 + kt, lB1);
    __syncthreads();
    s16x8 af[4], bf[4];
#pragma unroll
    for (int m2 = 0; m2 < 4; m2++) af[m2] = *(const s16x8*)(lA + (wr + m2 * 16 + r) * 32 + g * 8);
#pragma unroll
    for (int n2 = 0; n2 < 4; n2++) bf[n2] = *(const s16x8*)(lB + (wc + n2 * 16 + r) * 32 + g * 8);
#pragma unroll
    for (int m2 = 0; m2 < 4; m2++)
#pragma unroll
      for (int n2 = 0; n2 < 4; n2++)
        acc[m2][n2] = __builtin_amdgcn_mfma_f32_16x16x32_bf16(af[m2], bf[n2], acc[m2][n2], 0, 0, 0);
  }
#pragma unroll
  for (int m2 = 0; m2 < 4; m2++)
#pragma unroll
    for (int n2 = 0; n2 < 4; n2++)
#pragma unroll
      for (int jj = 0; jj < 4; jj++)
        C[(size_t)(bm + wr + m2 * 16 + g * 4 + jj) * N + (bn + wc + n2 * 16 + r)] =
            acc[m2][n2][jj];
}

// ---------- causal GQA flash attention ----------
// Q [b][28][S][128] bf16, K [b][4][S][128] bf16, Vt [b][4][128][S] bf16
// AO (B*S x 3584) bf16.  1 wave / (b,h,16-row q-tile).  KV head = h % 4 (jnp.tile).
__global__ __launch_bounds__(64) void attn_kernel(const u16* __restrict__ Q,
                                                  const u16* __restrict__ K,
                                                  const u16* __restrict__ Vt,
                                                  u16* __restrict__ AO) {
  constexpr int S = 2048, NH = 28, NKV = 4, D = 128;
  __shared__ u16 Pl[2][16 * 32];
  const int lane = threadIdx.x;
  const int r = lane & 15, g = lane >> 4;
  const int qt = blockIdx.x, h = blockIdx.y, b = blockIdx.z;
  const int q0 = qt * 16;
  const int kh = h & 3;
  const u16* Qb = Q + ((size_t)(b * NH + h) * S + q0) * D;
  const u16* Kb = K + ((size_t)(b * NKV + kh) * S) * D;
  const u16* Vb = Vt + ((size_t)(b * NKV + kh) * D) * S;

  s16x8 qf[4];
#pragma unroll
  for (int kb = 0; kb < 4; kb++)
    qf[kb] = *(const s16x8*)(Qb + (size_t)r * D + kb * 32 + g * 8);

  f32x4 o[8];
#pragma unroll
  for (int c = 0; c < 8; c++) o[c] = (f32x4){0.f, 0.f, 0.f, 0.f};
  float m = -1e30f, lsum = 0.f;
  const float scale = 0.08838834764831845f;  // 1/sqrt(128)
  const int qg = q0 + r;

  for (int j = 0; j <= q0; j += 32) {
    // QK^T, swapped operands: D[kv_local][q_local]
    f32x4 st0 = (f32x4){0.f, 0.f, 0.f, 0.f};
    f32x4 st1 = (f32x4){0.f, 0.f, 0.f, 0.f};
#pragma unroll
    for (int kb = 0; kb < 4; kb++) {
      s16x8 kf = *(const s16x8*)(Kb + (size_t)(j + r) * D + kb * 32 + g * 8);
      st0 = __builtin_amdgcn_mfma_f32_16x16x32_bf16(kf, qf[kb], st0, 0, 0, 0);
    }
#pragma unroll
    for (int kb = 0; kb < 4; kb++) {
      s16x8 kf = *(const s16x8*)(Kb + (size_t)(j + 16 + r) * D + kb * 32 + g * 8);
      st1 = __builtin_amdgcn_mfma_f32_16x16x32_bf16(kf, qf[kb], st1, 0, 0, 0);
    }
    float s8[8];
#pragma unroll
    for (int jj = 0; jj < 4; jj++) {
      int kv0 = j + g * 4 + jj, kv1 = kv0 + 16;
      s8[jj]     = (kv0 > qg) ? -1e30f : st0[jj] * scale;
      s8[jj + 4] = (kv1 > qg) ? -1e30f : st1[jj] * scale;
    }
    float pm = s8[0];
#pragma unroll
    for (int i2 = 1; i2 < 8; i2++) pm = fmaxf(pm, s8[i2]);
    pm = fmaxf(pm, __shfl_xor(pm, 16));
    pm = fmaxf(pm, __shfl_xor(pm, 32));
    float mnew = fmaxf(m, pm);
    float f = __expf(m - mnew);
    float psum = 0.f;
    u16 pb[8];
#pragma unroll
    for (int i2 = 0; i2 < 8; i2++) {
      float p = __expf(s8[i2] - mnew);
      psum += p;
      pb[i2] = f2bf(p);
    }
    psum += __shfl_xor(psum, 16);
    psum += __shfl_xor(psum, 32);
    lsum = lsum * f + psum;
    m = mnew;
    // stage P^T into LDS as P[q=16][kv=32] bf16 (double-buffered)
    int sel = (j >> 5) & 1;
    s16x4 p0 = {(short)pb[0], (short)pb[1], (short)pb[2], (short)pb[3]};
    s16x4 p1 = {(short)pb[4], (short)pb[5], (short)pb[6], (short)pb[7]};
    *(s16x4*)(&Pl[sel][r * 32 + g * 4]) = p0;
    *(s16x4*)(&Pl[sel][r * 32 + 16 + g * 4]) = p1;
    float fB[4];
#pragma unroll
    for (int jj = 0; jj < 4; jj++) fB[jj] = __shfl(f, g * 4 + jj);
    s16x8 pa = *(const s16x8*)(&Pl[sel][r * 32 + g * 8]);
#pragma unroll
    for (int c = 0; c < 8; c++) {
      f32x4 oc = o[c];
      oc.x *= fB[0]; oc.y *= fB[1]; oc.z *= fB[2]; oc.w *= fB[3];
      s16x8 vf = *(const s16x8*)(Vb + (size_t)(c * 16 + r) * S + j + g * 8);
      o[c] = __builtin_amdgcn_mfma_f32_16x16x32_bf16(pa, vf, oc, 0, 0, 0);
    }
  }
  float lB[4];
#pragma unroll
  for (int jj = 0; jj < 4; jj++) lB[jj] = __shfl(lsum, g * 4 + jj);
#pragma unroll
  for (int c = 0; c < 8; c++)
#pragma unroll
    for (int jj = 0; jj < 4; jj++) {
      float val = o[c][jj] / lB[jj];
      AO[(size_t)(b * S + q0 + g * 4 + jj) * 3584 + h * 128 + c * 16 + r] = f2bf(val);
    }
}

// ---------- workspace layout (bytes) ----------
static const size_t OFF_XBF = 0;            // 4096x3584 bf16
static const size_t OFF_WQT = 29360128;     // 3584x3584 bf16 (Wq^T)
static const size_t OFF_WKT = 55050240;     // 512x3584 bf16
static const size_t OFF_WVT = 58720256;     // 512x3584 bf16
static const size_t OFF_WOT = 62390272;     // 3584x3584 bf16
static const size_t OFF_TAB = 88080384;     // 2048x64 float2
static const size_t OFF_QBF = 89128960;     // [2][28][2048][128] bf16
static const size_t OFF_KBF = 118489088;    // [2][4][2048][128] bf16
static const size_t OFF_VT  = 122683392;    // [2][4][128][2048] bf16
static const size_t OFF_QP  = 126877696;    // 4096x3584 f32 (reused: AO bf16)
static const size_t OFF_KP  = 185597952;    // 4096x512 f32
static const size_t OFF_VP  = 193986560;    // 4096x512 f32
// total: 202375168 bytes

extern "C" void kernel_launch(void* const* d_in, const int* in_sizes, int n_in,
                              void* d_out, int out_size, void* d_ws, size_t ws_size,
                              hipStream_t stream) {
  const float* X  = (const float*)d_in[0];
  const float* Wq = (const float*)d_in[1];
  const float* Wk = (const float*)d_in[2];
  const float* Wv = (const float*)d_in[3];
  const float* Wo = (const float*)d_in[4];
  float* out = (float*)d_out;
  char* ws = (char*)d_ws;

  u16* Xbf = (u16*)(ws + OFF_XBF);
  u16* WqT = (u16*)(ws + OFF_WQT);
  u16* WkT = (u16*)(ws + OFF_WKT);
  u16* WvT = (u16*)(ws + OFF_WVT);
  u16* WoT = (u16*)(ws + OFF_WOT);
  float2* tab = (float2*)(ws + OFF_TAB);
  u16* Qbf = (u16*)(ws + OFF_QBF);
  u16* Kbf = (u16*)(ws + OFF_KBF);
  u16* Vtb = (u16*)(ws + OFF_VT);
  float* Qp = (float*)(ws + OFF_QP);
  float* Kp = (float*)(ws + OFF_KP);
  float* Vp = (float*)(ws + OFF_VP);
  u16* AO  = (u16*)(ws + OFF_QP);  // reuse Qp region after rope_pack

  // conversions
  cvt_bf16<<<14336, 256, 0, stream>>>(X, Xbf, 3670016);
  transpose_cvt<<<dim3(112, 112), 256, 0, stream>>>(Wq, WqT, 3584, 3584);
  transpose_cvt<<<dim3(16, 112), 256, 0, stream>>>(Wk, WkT, 3584, 512);
  transpose_cvt<<<dim3(16, 112), 256, 0, stream>>>(Wv, WvT, 3584, 512);
  transpose_cvt<<<dim3(112, 112), 256, 0, stream>>>(Wo, WoT, 3584, 3584);
  rope_table<<<2048, 64, 0, stream>>>(tab);

  // projections
  gemm_bt<<<dim3(28, 32), 256, 0, stream>>>(Xbf, WqT, Qp, 4096, 3584, 3584);
  gemm_bt<<<dim3(4, 32), 256, 0, stream>>>(Xbf, WkT, Kp, 4096, 512, 3584);
  gemm_bt<<<dim3(4, 32), 256, 0, stream>>>(Xbf, WvT, Vp, 4096, 512, 3584);

  // rope + pack
  rope_pack<<<28672, 256, 0, stream>>>(Qp, tab, Qbf, 28);
  rope_pack<<<4096, 256, 0, stream>>>(Kp, tab, Kbf, 4);
  pack_vt<<<dim3(64, 4, 8), 256, 0, stream>>>(Vp, Vtb);

  // attention
  attn_kernel<<<dim3(128, 28, 2), 64, 0, stream>>>(Qbf, Kbf, Vtb, AO);

  // output projection
  gemm_bt<<<dim3(28, 32), 256, 0, stream>>>(AO, WoT, out, 4096, 3584, 3584);
}

// Round 3
// 724.186 us; speedup vs baseline: 1.5645x; 1.5645x over previous
//
#include <hip/hip_runtime.h>
#include <hip/hip_bf16.h>

typedef __attribute__((ext_vector_type(4))) float f32x4;
typedef __attribute__((ext_vector_type(8))) short s16x8;
typedef __attribute__((ext_vector_type(4))) short s16x4;
typedef unsigned short u16;

// ---------- helpers ----------
__device__ __forceinline__ u16 f2bf(float f) {
  union { float f; unsigned int u; } v; v.f = f;
  unsigned int r = v.u + 0x7fffu + ((v.u >> 16) & 1u);  // RNE
  return (u16)(r >> 16);
}

__device__ __forceinline__ void gload_lds16(const void* g, void* l) {
  __builtin_amdgcn_global_load_lds(
      (const __attribute__((address_space(1))) void*)g,
      (__attribute__((address_space(3))) void*)l, 16, 0, 0);
}

// ---------- elementwise f32 -> bf16 (vectorized) ----------
__global__ __launch_bounds__(256) void cvt_bf16(const float* __restrict__ in,
                                                u16* __restrict__ outp, int nquad) {
  int i = blockIdx.x * 256 + threadIdx.x;
  if (i >= nquad) return;
  f32x4 v = *(const f32x4*)(in + (size_t)i * 4);
  s16x4 o;
  o.x = (short)f2bf(v.x); o.y = (short)f2bf(v.y);
  o.z = (short)f2bf(v.z); o.w = (short)f2bf(v.w);
  *(s16x4*)(outp + (size_t)i * 4) = o;
}

// ---------- transpose + convert: in (R x C) f32 row-major -> out (C x R) bf16 ----------
__global__ __launch_bounds__(256) void transpose_cvt(const float* __restrict__ in,
                                                     u16* __restrict__ outp, int R, int C) {
  __shared__ float t[32][33];
  int c0 = blockIdx.x * 32, r0 = blockIdx.y * 32;
  int tx = threadIdx.x & 31, ty = threadIdx.x >> 5;  // 32 x 8
#pragma unroll
  for (int i = 0; i < 32; i += 8) t[ty + i][tx] = in[(size_t)(r0 + ty + i) * C + c0 + tx];
  __syncthreads();
#pragma unroll
  for (int i = 0; i < 32; i += 8)
    outp[(size_t)(c0 + ty + i) * R + r0 + tx] = f2bf(t[tx][ty + i]);
}

// ---------- RoPE table (matches the reference's interleaved-then-split layout) ----------
__global__ void rope_table(float2* __restrict__ tab) {
  int p = blockIdx.x, e = threadIdx.x;
  int j = e >> 1;
  float f1 = powf(1.0e6f, -(float)j / 64.0f);
  float f2 = powf(1.0e6f, -(float)(j + 32) / 64.0f);
  float a1 = (float)p * f1, a2 = (float)p * f2;
  float S = (e & 1) ? cosf(a1) : sinf(a1);
  float C = (e & 1) ? cosf(a2) : sinf(a2);
  tab[p * 64 + e] = make_float2(S, C);
}

// ---------- RoPE + head-pack: P (B*S x ldp) f32 -> out [b][h][s][128] bf16 ----------
__global__ __launch_bounds__(256) void rope_pack(const float* __restrict__ P,
                                                 const float2* __restrict__ tab,
                                                 u16* __restrict__ outp, int nh, int ldp,
                                                 float scale) {
  int idx = blockIdx.x * 4 + (threadIdx.x >> 6);  // over (b*nh+h)*2048+s
  int e = threadIdx.x & 63;
  int s = idx & 2047;
  int bh = idx >> 11;
  int b = bh / nh, h = bh - b * nh;
  size_t prow = ((size_t)(b * 2048 + s)) * (size_t)ldp + (size_t)h * 128;
  float x1 = P[prow + e], x2 = P[prow + e + 64];
  float2 t = tab[s * 64 + e];
  float o1 = (x1 * t.y - x2 * t.x) * scale;
  float o2 = (x2 * t.y + x1 * t.x) * scale;
  size_t orow = (size_t)idx * 128;
  outp[orow + e] = f2bf(o1);
  outp[orow + e + 64] = f2bf(o2);
}

// ---------- V pack+transpose: KVp rows (stride ldp, V at col off) -> Vt [b][kh][128][S] bf16 ----------
__global__ __launch_bounds__(256) void pack_vt(const float* __restrict__ Vp,
                                               u16* __restrict__ Vt, int ldp, int coff) {
  __shared__ float t[32][33];
  int bk = blockIdx.z;               // b*4+kh
  int b = bk >> 2, kh = bk & 3;
  int s0 = blockIdx.x * 32, d0 = blockIdx.y * 32;
  int tx = threadIdx.x & 31, ty = threadIdx.x >> 5;
  const float* in = Vp + (size_t)(b * 2048) * ldp + coff + kh * 128;
#pragma unroll
  for (int i = 0; i < 32; i += 8) t[ty + i][tx] = in[(size_t)(s0 + ty + i) * ldp + d0 + tx];
  __syncthreads();
  u16* outp = Vt + (size_t)bk * 128 * 2048;
#pragma unroll
  for (int i = 0; i < 32; i += 8)
    outp[(size_t)(d0 + ty + i) * 2048 + s0 + tx] = f2bf(t[tx][ty + i]);
}

// ---------- GEMM: C (MxN f32) = A (MxK bf16) * BT (NxK bf16)^T ; 128x128 tile ----------
__global__ __launch_bounds__(256) void gemm_bt(const u16* __restrict__ A,
                                               const u16* __restrict__ BT,
                                               float* __restrict__ C, int M, int N, int K) {
  __shared__ u16 lA[128 * 32];
  __shared__ u16 lB[128 * 32];
  const int tid = threadIdx.x;
  const int lane = tid & 63, wave = tid >> 6;
  const int bm = blockIdx.y * 128, bn = blockIdx.x * 128;
  const int wr = (wave >> 1) * 64, wc = (wave & 1) * 64;
  const int r = lane & 15, g = lane >> 4;

  f32x4 acc[4][4];
#pragma unroll
  for (int i = 0; i < 4; i++)
#pragma unroll
    for (int j = 0; j < 4; j++) acc[i][j] = (f32x4){0.f, 0.f, 0.f, 0.f};

  const int o0 = wave * 2048 + lane * 16;
  const int row0 = o0 >> 6, cb0 = (o0 & 63) >> 1;
  const int o1 = o0 + 1024;
  const int row1 = o1 >> 6, cb1 = (o1 & 63) >> 1;
  const u16* a0 = A + (size_t)(bm + row0) * K + cb0;
  const u16* a1 = A + (size_t)(bm + row1) * K + cb1;
  const u16* b0 = BT + (size_t)(bn + row0) * K + cb0;
  const u16* b1 = BT + (size_t)(bn + row1) * K + cb1;
  u16* lA0 = lA + wave * 2 * 512; u16* lA1 = lA + (wave * 2 + 1) * 512;
  u16* lB0 = lB + wave * 2 * 512; u16* lB1 = lB + (wave * 2 + 1) * 512;

  for (int kt = 0; kt < K; kt += 32) {
    __syncthreads();
    gload_lds16(a0 + kt, lA0);
    gload_lds16(a1 + kt, lA1);
    gload_lds16(b0 + kt, lB0);
    gload_lds16(b1 + kt, lB1);
    __syncthreads();
    s16x8 af[4], bf[4];
#pragma unroll
    for (int m2 = 0; m2 < 4; m2++) af[m2] = *(const s16x8*)(lA + (wr + m2 * 16 + r) * 32 + g * 8);
#pragma unroll
    for (int n2 = 0; n2 < 4; n2++) bf[n2] = *(const s16x8*)(lB + (wc + n2 * 16 + r) * 32 + g * 8);
#pragma unroll
    for (int m2 = 0; m2 < 4; m2++)
#pragma unroll
      for (int n2 = 0; n2 < 4; n2++)
        acc[m2][n2] = __builtin_amdgcn_mfma_f32_16x16x32_bf16(af[m2], bf[n2], acc[m2][n2], 0, 0, 0);
  }
#pragma unroll
  for (int m2 = 0; m2 < 4; m2++)
#pragma unroll
    for (int n2 = 0; n2 < 4; n2++)
#pragma unroll
      for (int jj = 0; jj < 4; jj++)
        C[(size_t)(bm + wr + m2 * 16 + g * 4 + jj) * N + (bn + wc + n2 * 16 + r)] =
            acc[m2][n2][jj];
}

// ---------- causal GQA flash attention, 4-wave blocks, LDS-staged K/V ----------
// Q [b][28][S][128] bf16 (pre-scaled), K [b][4][S][128] bf16, Vt [b][4][128][S] bf16
// AO (B*S x 3584) bf16.  Block: QBLK=64 rows (wave w owns rows q0b+16w..+15). KVBLK=32.
__global__ __launch_bounds__(256, 4) void attn_kernel(const u16* __restrict__ Q,
                                                      const u16* __restrict__ K,
                                                      const u16* __restrict__ Vt,
                                                      u16* __restrict__ AO) {
  constexpr int S = 2048, NH = 28, NKV = 4, D = 128;
  __shared__ u16 Kl[2][32 * 128];  // [row][256B], stored byte ^= (row&7)<<4
  __shared__ u16 Vl[2][32 * 128];  // [d][64B],   stored byte ^= ((d>>1)&7)<<4
  const int tid = threadIdx.x;
  const int lane = tid & 63, w = tid >> 6;
  const int r = lane & 15, g = lane >> 4;
  const int qt = (int)gridDim.x - 1 - (int)blockIdx.x;  // heavy tiles first
  const int h = blockIdx.y, b = blockIdx.z;
  const int q0b = qt * 64;
  const int q0 = q0b + w * 16;
  const int kh = h & 3;
  const u16* Qb = Q + ((size_t)(b * NH + h) * S + q0) * D;
  const u16* Kb = K + ((size_t)(b * NKV + kh) * S) * D;
  const u16* Vb = Vt + ((size_t)(b * NKV + kh) * D) * S;

  s16x8 qf[4];
#pragma unroll
  for (int kb = 0; kb < 4; kb++)
    qf[kb] = *(const s16x8*)(Qb + (size_t)r * D + kb * 32 + g * 8);

  // staging source precompute (pre-swizzled global addrs; LDS dest is linear)
  const u16* srcK[2];
  const u16* srcV[2];
#pragma unroll
  for (int i = 0; i < 2; i++) {
    int o = w * 2048 + i * 1024 + lane * 16;  // linear byte offset in 8KB tile
    int krow = o >> 8;
    int kcol = ((o & 255) ^ ((krow & 7) << 4)) >> 1;
    srcK[i] = Kb + (size_t)krow * D + kcol;
    int p = o ^ (((o >> 7) & 7) << 4);  // involution: logical byte
    int vd = p >> 6, vs = (p & 63) >> 1;
    srcV[i] = Vb + (size_t)vd * S + vs;
  }

  f32x4 o8[8];
#pragma unroll
  for (int c = 0; c < 8; c++) o8[c] = (f32x4){0.f, 0.f, 0.f, 0.f};
  float m = -1e30f, lsum = 0.f;
  const int qg = q0 + r;
  const int NT = 2 * qt + 2;

  // prologue stage
#pragma unroll
  for (int i = 0; i < 2; i++) {
    gload_lds16(srcK[i], (u16*)Kl[0] + w * 1024 + i * 512);
    gload_lds16(srcV[i], (u16*)Vl[0] + w * 1024 + i * 512);
  }
  __syncthreads();

  int cur = 0;
  for (int t = 0; t < NT; ++t) {
    const int j = t * 32;
    const bool hasNext = (t + 1 < NT);
    if (hasNext) {
      const int jn = j + 32;
#pragma unroll
      for (int i = 0; i < 2; i++) {
        gload_lds16(srcK[i] + (size_t)jn * D, (u16*)Kl[cur ^ 1] + w * 1024 + i * 512);
        gload_lds16(srcV[i] + jn, (u16*)Vl[cur ^ 1] + w * 1024 + i * 512);
      }
    }
    if (j <= q0 + 15) {  // wave-uniform active check
      // ---- QK^T (swapped): lane holds P[kv=g*4+jj][q=r] ----
      f32x4 st0 = (f32x4){0.f, 0.f, 0.f, 0.f};
      f32x4 st1 = (f32x4){0.f, 0.f, 0.f, 0.f};
      const int swz = (r & 7) << 4;
      const char* Kc = (const char*)Kl[cur];
#pragma unroll
      for (int kb = 0; kb < 4; kb++) {
        int cb = (kb * 64 + g * 16) ^ swz;
        s16x8 kf = *(const s16x8*)(Kc + r * 256 + cb);
        st0 = __builtin_amdgcn_mfma_f32_16x16x32_bf16(kf, qf[kb], st0, 0, 0, 0);
      }
#pragma unroll
      for (int kb = 0; kb < 4; kb++) {
        int cb = (kb * 64 + g * 16) ^ swz;
        s16x8 kf = *(const s16x8*)(Kc + (r + 16) * 256 + cb);
        st1 = __builtin_amdgcn_mfma_f32_16x16x32_bf16(kf, qf[kb], st1, 0, 0, 0);
      }
      float s8v[8];
      if (j + 31 <= q0) {  // fully unmasked tile
#pragma unroll
        for (int jj = 0; jj < 4; jj++) { s8v[jj] = st0[jj]; s8v[jj + 4] = st1[jj]; }
      } else {
#pragma unroll
        for (int jj = 0; jj < 4; jj++) {
          int kv0 = j + g * 4 + jj;
          s8v[jj] = (kv0 > qg) ? -1e30f : st0[jj];
          s8v[jj + 4] = (kv0 + 16 > qg) ? -1e30f : st1[jj];
        }
      }
      // ---- online softmax (row = q = r, reduce over g-lanes) ----
      float pm = fmaxf(fmaxf(fmaxf(s8v[0], s8v[1]), fmaxf(s8v[2], s8v[3])),
                       fmaxf(fmaxf(s8v[4], s8v[5]), fmaxf(s8v[6], s8v[7])));
      pm = fmaxf(pm, __shfl_xor(pm, 16));
      pm = fmaxf(pm, __shfl_xor(pm, 32));
      float mnew = fmaxf(m, pm);
      float fr = __expf(m - mnew);
      float pv[8], psum = 0.f;
#pragma unroll
      for (int i2 = 0; i2 < 8; i2++) { pv[i2] = __expf(s8v[i2] - mnew); psum += pv[i2]; }
      psum += __shfl_xor(psum, 16);
      psum += __shfl_xor(psum, 32);
      lsum = lsum * fr + psum;
      m = mnew;
      // ---- P -> bf16 ----
      // lane (r,g) holds pk[2*hi+p] = P[q=r][kvl=16*hi+4g+2p .. +1]
      unsigned pk[4];
#pragma unroll
      for (int i2 = 0; i2 < 4; i2++) {
        __hip_bfloat162 hv = __float22bfloat162_rn(make_float2(pv[2 * i2], pv[2 * i2 + 1]));
        union { __hip_bfloat162 h; unsigned u; } cv; cv.h = hv; pk[i2] = cv.u;
      }
      // ---- redistribute to A-fragment layout: dest (r,g) slot d needs
      //      pk[2*(g>>1)+(d&1)] from lane r + 32*(g&1) + 16*(d>>1).
      //      Pull both candidate pairs from both lanes, select by dest g. ----
      int L0 = r + ((g & 1) << 5);
      unsigned a0 = (unsigned)__shfl((int)pk[0], L0);
      unsigned a1 = (unsigned)__shfl((int)pk[1], L0);
      unsigned a2 = (unsigned)__shfl((int)pk[2], L0);
      unsigned a3 = (unsigned)__shfl((int)pk[3], L0);
      unsigned b0 = (unsigned)__shfl((int)pk[0], L0 + 16);
      unsigned b1 = (unsigned)__shfl((int)pk[1], L0 + 16);
      unsigned b2 = (unsigned)__shfl((int)pk[2], L0 + 16);
      unsigned b3 = (unsigned)__shfl((int)pk[3], L0 + 16);
      union { unsigned u[4]; s16x8 v; } pu;
      pu.u[0] = (g < 2) ? a0 : a2;
      pu.u[1] = (g < 2) ? a1 : a3;
      pu.u[2] = (g < 2) ? b0 : b2;
      pu.u[3] = (g < 2) ? b1 : b3;
      s16x8 pa = pu.v;
      float fB[4];
#pragma unroll
      for (int jj = 0; jj < 4; jj++) fB[jj] = __shfl(fr, g * 4 + jj);
      // ---- PV ----
      const char* Vc = (const char*)Vl[cur];
#pragma unroll
      for (int c = 0; c < 8; c++) {
        int pbyte = (c * 16 + r) * 64 + g * 16;
        int vaddr = pbyte ^ ((r >> 1) << 4);
        s16x8 vf = *(const s16x8*)(Vc + vaddr);
        f32x4 oc = o8[c];
        oc.x *= fB[0]; oc.y *= fB[1]; oc.z *= fB[2]; oc.w *= fB[3];
        o8[c] = __builtin_amdgcn_mfma_f32_16x16x32_bf16(pa, vf, oc, 0, 0, 0);
      }
    }
    __syncthreads();
    cur ^= 1;
  }

  float lB[4];
#pragma unroll
  for (int jj = 0; jj < 4; jj++) lB[jj] = __shfl(lsum, g * 4 + jj);
#pragma unroll
  for (int c = 0; c < 8; c++)
#pragma unroll
    for (int jj = 0; jj < 4; jj++) {
      float val = o8[c][jj] / lB[jj];
      AO[(size_t)(b * S + q0 + g * 4 + jj) * 3584 + h * 128 + c * 16 + r] = f2bf(val);
    }
}

// ---------- workspace layout (bytes) ----------
static const size_t OFF_XBF = 0;            // 4096x3584 bf16
static const size_t OFF_WQT = 29360128;     // 3584x3584 bf16
static const size_t OFF_WKT = 55050240;     // 512x3584 bf16   (contiguous with WVT ->
static const size_t OFF_WVT = 58720256;     // 512x3584 bf16    combined [1024][3584])
static const size_t OFF_WOT = 62390272;     // 3584x3584 bf16
static const size_t OFF_TAB = 88080384;     // 2048x64 float2
static const size_t OFF_QBF = 89128960;     // [2][28][2048][128] bf16
static const size_t OFF_KBF = 118489088;    // [2][4][2048][128] bf16
static const size_t OFF_VT  = 122683392;    // [2][4][128][2048] bf16
static const size_t OFF_QP  = 126877696;    // 4096x3584 f32 (reused: AO bf16)
static const size_t OFF_KVP = 185597952;    // 4096x1024 f32
// total: 202375168 bytes

extern "C" void kernel_launch(void* const* d_in, const int* in_sizes, int n_in,
                              void* d_out, int out_size, void* d_ws, size_t ws_size,
                              hipStream_t stream) {
  const float* X  = (const float*)d_in[0];
  const float* Wq = (const float*)d_in[1];
  const float* Wk = (const float*)d_in[2];
  const float* Wv = (const float*)d_in[3];
  const float* Wo = (const float*)d_in[4];
  float* out = (float*)d_out;
  char* ws = (char*)d_ws;

  u16* Xbf = (u16*)(ws + OFF_XBF);
  u16* WqT = (u16*)(ws + OFF_WQT);
  u16* WkT = (u16*)(ws + OFF_WKT);
  u16* WvT = (u16*)(ws + OFF_WVT);
  u16* WoT = (u16*)(ws + OFF_WOT);
  float2* tab = (float2*)(ws + OFF_TAB);
  u16* Qbf = (u16*)(ws + OFF_QBF);
  u16* Kbf = (u16*)(ws + OFF_KBF);
  u16* Vtb = (u16*)(ws + OFF_VT);
  float* Qp = (float*)(ws + OFF_QP);
  float* KVp = (float*)(ws + OFF_KVP);
  u16* AO  = (u16*)(ws + OFF_QP);  // reuse Qp region after rope_pack

  // conversions
  cvt_bf16<<<14336, 256, 0, stream>>>(X, Xbf, 3670016);
  transpose_cvt<<<dim3(112, 112), 256, 0, stream>>>(Wq, WqT, 3584, 3584);
  transpose_cvt<<<dim3(16, 112), 256, 0, stream>>>(Wk, WkT, 3584, 512);
  transpose_cvt<<<dim3(16, 112), 256, 0, stream>>>(Wv, WvT, 3584, 512);
  transpose_cvt<<<dim3(112, 112), 256, 0, stream>>>(Wo, WoT, 3584, 3584);
  rope_table<<<2048, 64, 0, stream>>>(tab);

  // projections (K and V fused: BT = [WkT ; WvT] is contiguous, N=1024)
  gemm_bt<<<dim3(28, 32), 256, 0, stream>>>(Xbf, WqT, Qp, 4096, 3584, 3584);
  gemm_bt<<<dim3(8, 32), 256, 0, stream>>>(Xbf, WkT, KVp, 4096, 1024, 3584);

  // rope + pack (scale folded into Q)
  rope_pack<<<28672, 256, 0, stream>>>(Qp, tab, Qbf, 28, 3584, 0.08838834764831845f);
  rope_pack<<<4096, 256, 0, stream>>>(KVp, tab, Kbf, 4, 1024, 1.0f);
  pack_vt<<<dim3(64, 4, 8), 256, 0, stream>>>(KVp, Vtb, 1024, 512);

  // attention
  attn_kernel<<<dim3(32, 28, 2), 256, 0, stream>>>(Qbf, Kbf, Vtb, AO);

  // output projection
  gemm_bt<<<dim3(28, 32), 256, 0, stream>>>(AO, WoT, out, 4096, 3584, 3584);
}